// Round 1
// baseline (24.469 us; speedup 1.0000x reference)
//
#include <hip/hip_runtime.h>

#define NROWS 4096
#define DDIM 256
#define BLOCKS_PER_B 64           // 64 blocks per instance, 64 rows each
#define ROWS_PER_BLOCK (NROWS / BLOCKS_PER_B)  // 64

// Kernel 1: each block computes the partial sum of cosine similarities over
// its 64-row chunk of one instance b, masked to n < len[b].
// One wave (64 lanes) per row; lane l owns elements [4l, 4l+4).
__global__ __launch_bounds__(256) void cos_partial_kernel(
    const float* __restrict__ stat, const float* __restrict__ con,
    const int* __restrict__ lens, float* __restrict__ ws) {
  const int blk  = blockIdx.x;
  const int b    = blk / BLOCKS_PER_B;
  const int j    = blk % BLOCKS_PER_B;
  const int wave = threadIdx.x >> 6;
  const int lane = threadIdx.x & 63;

  const int len = lens[b];
  const int n0  = j * ROWS_PER_BLOCK;

  float acc = 0.0f;
  if (n0 < len) {
    const int nEnd = min(n0 + ROWS_PER_BLOCK, len);
    for (int n = n0 + wave; n < nEnd; n += 4) {
      const size_t base = ((size_t)b * NROWS + (size_t)n) * DDIM + (size_t)(lane << 2);
      const float4 a = *reinterpret_cast<const float4*>(stat + base);
      const float4 c = *reinterpret_cast<const float4*>(con + base);

      float dot = a.x * c.x + a.y * c.y + a.z * c.z + a.w * c.w;
      float ns  = a.x * a.x + a.y * a.y + a.z * a.z + a.w * a.w;
      float nc  = c.x * c.x + c.y * c.y + c.z * c.z + c.w * c.w;

      // 64-lane butterfly reduction (wave = 64 on CDNA)
      #pragma unroll
      for (int off = 32; off > 0; off >>= 1) {
        dot += __shfl_xor(dot, off);
        ns  += __shfl_xor(ns,  off);
        nc  += __shfl_xor(nc,  off);
      }
      const float denom = fmaxf(sqrtf(ns), 1e-8f) * fmaxf(sqrtf(nc), 1e-8f);
      acc += dot / denom;   // all lanes hold identical value; lane 0 publishes
    }
  }

  __shared__ float sh[4];
  if (lane == 0) sh[wave] = acc;
  __syncthreads();
  if (threadIdx.x == 0) ws[blk] = sh[0] + sh[1] + sh[2] + sh[3];
}

// Kernel 2: single block. Wave w reduces the 64 partials of instance b=w,
// thread 0 combines the B per-instance losses sequentially (deterministic).
__global__ __launch_bounds__(1024) void cos_final_kernel(
    const float* __restrict__ ws, const int* __restrict__ lens,
    float* __restrict__ out, int B) {
  const int w    = threadIdx.x >> 6;   // = b
  const int lane = threadIdx.x & 63;

  float v = 0.0f;
  if (w < B) v = ws[w * BLOCKS_PER_B + lane];
  #pragma unroll
  for (int off = 32; off > 0; off >>= 1) v += __shfl_xor(v, off);

  __shared__ float sh[16];
  if (lane == 0 && w < B) {
    const int len = lens[w];
    sh[w] = (len > 0) ? (1.0f - v / (float)len) : 0.0f;
  }
  __syncthreads();
  if (threadIdx.x == 0) {
    float t = 0.0f;
    for (int i = 0; i < B; ++i) t += sh[i];
    out[0] = t / (float)B;
  }
}

extern "C" void kernel_launch(void* const* d_in, const int* in_sizes, int n_in,
                              void* d_out, int out_size, void* d_ws, size_t ws_size,
                              hipStream_t stream) {
  const float* stat = (const float*)d_in[0];
  const float* con  = (const float*)d_in[1];
  const int*   lens = (const int*)d_in[2];
  float*       out  = (float*)d_out;
  float*       ws   = (float*)d_ws;

  const int B = in_sizes[2];           // 16

  dim3 grid1(B * BLOCKS_PER_B);        // 1024 blocks
  dim3 blk1(256);
  hipLaunchKernelGGL(cos_partial_kernel, grid1, blk1, 0, stream, stat, con, lens, ws);

  dim3 grid2(1);
  dim3 blk2(64 * B);                   // 1024 threads: one wave per instance
  hipLaunchKernelGGL(cos_final_kernel, grid2, blk2, 0, stream, ws, lens, out, B);
}

// Round 2
// 22.639 us; speedup vs baseline: 1.0808x; 1.0808x over previous
//
#include <hip/hip_runtime.h>

#define NROWS 4096
#define DDIM 256
#define BLOCKS_PER_B 64   // 64 blocks per instance; block j handles rows n ≡ j (mod 64)

// Kernel 1: block (b, j) sums cosine similarities over rows {n < len[b] : n ≡ j mod 64}.
// Wave w (of 4) handles n = j + 64*w, j + 64*w + 256, ... -> per-wave work balanced
// to within one row across the whole grid, independent of the length distribution.
// One wave per row: lane l owns elements [4l, 4l+4) of D=256 (one float4 each tensor).
__global__ __launch_bounds__(256) void cos_partial_kernel(
    const float* __restrict__ stat, const float* __restrict__ con,
    const int* __restrict__ lens, float* __restrict__ ws) {
  const int blk  = blockIdx.x;
  const int b    = blk / BLOCKS_PER_B;
  const int j    = blk % BLOCKS_PER_B;
  const int wave = threadIdx.x >> 6;
  const int lane = threadIdx.x & 63;

  const int len = lens[b];

  float acc = 0.0f;
  for (int n = j + (wave << 6); n < len; n += 256) {
    const size_t base = ((size_t)b * NROWS + (size_t)n) * DDIM + (size_t)(lane << 2);
    const float4 a = *reinterpret_cast<const float4*>(stat + base);
    const float4 c = *reinterpret_cast<const float4*>(con + base);

    float dot = a.x * c.x + a.y * c.y + a.z * c.z + a.w * c.w;
    float ns  = a.x * a.x + a.y * a.y + a.z * a.z + a.w * a.w;
    float nc  = c.x * c.x + c.y * c.y + c.z * c.z + c.w * c.w;

    // 64-lane butterfly reduction (wave = 64 on CDNA)
    #pragma unroll
    for (int off = 32; off > 0; off >>= 1) {
      dot += __shfl_xor(dot, off);
      ns  += __shfl_xor(ns,  off);
      nc  += __shfl_xor(nc,  off);
    }
    const float denom = fmaxf(sqrtf(ns), 1e-8f) * fmaxf(sqrtf(nc), 1e-8f);
    acc += dot / denom;   // identical across lanes
  }

  __shared__ float sh[4];
  if (lane == 0) sh[wave] = acc;
  __syncthreads();
  if (threadIdx.x == 0) ws[blk] = sh[0] + sh[1] + sh[2] + sh[3];
}

// Kernel 2: single block. Wave w reduces the 64 partials of instance b=w,
// thread 0 combines the B per-instance losses sequentially (deterministic).
__global__ __launch_bounds__(1024) void cos_final_kernel(
    const float* __restrict__ ws, const int* __restrict__ lens,
    float* __restrict__ out, int B) {
  const int w    = threadIdx.x >> 6;   // = b
  const int lane = threadIdx.x & 63;

  float v = 0.0f;
  if (w < B) v = ws[w * BLOCKS_PER_B + lane];
  #pragma unroll
  for (int off = 32; off > 0; off >>= 1) v += __shfl_xor(v, off);

  __shared__ float sh[16];
  if (lane == 0 && w < B) {
    const int len = lens[w];
    sh[w] = (len > 0) ? (1.0f - v / (float)len) : 0.0f;
  }
  __syncthreads();
  if (threadIdx.x == 0) {
    float t = 0.0f;
    for (int i = 0; i < B; ++i) t += sh[i];
    out[0] = t / (float)B;
  }
}

extern "C" void kernel_launch(void* const* d_in, const int* in_sizes, int n_in,
                              void* d_out, int out_size, void* d_ws, size_t ws_size,
                              hipStream_t stream) {
  const float* stat = (const float*)d_in[0];
  const float* con  = (const float*)d_in[1];
  const int*   lens = (const int*)d_in[2];
  float*       out  = (float*)d_out;
  float*       ws   = (float*)d_ws;

  const int B = in_sizes[2];           // 16

  dim3 grid1(B * BLOCKS_PER_B);        // 1024 blocks, all live, balanced work
  dim3 blk1(256);
  hipLaunchKernelGGL(cos_partial_kernel, grid1, blk1, 0, stream, stat, con, lens, ws);

  dim3 grid2(1);
  dim3 blk2(64 * B);                   // 1024 threads: one wave per instance
  hipLaunchKernelGGL(cos_final_kernel, grid2, blk2, 0, stream, ws, lens, out, B);
}

// Round 3
// 21.586 us; speedup vs baseline: 1.1336x; 1.0488x over previous
//
#include <hip/hip_runtime.h>

#define NROWS 4096
#define DDIM 256
#define BDIM 16               // B fixed by the reference
#define NBLOCKS 1024          // 4 waves/block * 1024 blocks = 4096 waves = NROWS

// Kernel 1: wave w (global, 0..4095) processes row n=w of EVERY instance b,
// skipping (b, n) with n >= len[b] (no memory traffic for skipped rows).
// Per-CU work is a stratified sample of the length survival function ->
// balanced to a few % independent of the length distribution.
// One wave per row: lane l owns elements [4l, 4l+4) (one float4 per tensor).
__global__ __launch_bounds__(256) void cos_partial_kernel(
    const float* __restrict__ stat, const float* __restrict__ con,
    const int* __restrict__ lens, float* __restrict__ ws) {
  const int widx = threadIdx.x >> 6;
  const int lane = threadIdx.x & 63;
  const int w    = (blockIdx.x << 2) + widx;   // 0..4095
  const int n    = w;                           // row within each instance

  int L[BDIM];
  #pragma unroll
  for (int b = 0; b < BDIM; ++b) L[b] = lens[b];

  float acc[BDIM];
  #pragma unroll
  for (int b = 0; b < BDIM; ++b) acc[b] = 0.0f;

  #pragma unroll
  for (int b = 0; b < BDIM; ++b) {
    if (n < L[b]) {   // wave-uniform branch; skipped rows cost no memory
      const size_t base = ((size_t)b * NROWS + (size_t)n) * DDIM + (size_t)(lane << 2);
      const float4 a = *reinterpret_cast<const float4*>(stat + base);
      const float4 c = *reinterpret_cast<const float4*>(con + base);

      float dot = a.x * c.x + a.y * c.y + a.z * c.z + a.w * c.w;
      float ns  = a.x * a.x + a.y * a.y + a.z * a.z + a.w * a.w;
      float nc  = c.x * c.x + c.y * c.y + c.z * c.z + c.w * c.w;

      #pragma unroll
      for (int off = 32; off > 0; off >>= 1) {
        dot += __shfl_xor(dot, off);
        ns  += __shfl_xor(ns,  off);
        nc  += __shfl_xor(nc,  off);
      }
      const float denom = fmaxf(sqrtf(ns), 1e-8f) * fmaxf(sqrtf(nc), 1e-8f);
      acc[b] = dot / denom;   // identical across lanes
    }
  }

  // Combine the block's 4 waves -> ws[b * NBLOCKS + blockIdx.x]
  __shared__ float sh[4][BDIM];
  if (lane == 0) {
    #pragma unroll
    for (int b = 0; b < BDIM; ++b) sh[widx][b] = acc[b];
  }
  __syncthreads();
  const int t = threadIdx.x;
  if (t < BDIM) {
    ws[t * NBLOCKS + blockIdx.x] = sh[0][t] + sh[1][t] + sh[2][t] + sh[3][t];
  }
}

// Kernel 2: single block, 1024 threads. Wave b reduces the 1024 partials of
// instance b (coalesced reads), thread 0 combines the B losses sequentially.
__global__ __launch_bounds__(1024) void cos_final_kernel(
    const float* __restrict__ ws, const int* __restrict__ lens,
    float* __restrict__ out, int B) {
  const int b    = threadIdx.x >> 6;
  const int lane = threadIdx.x & 63;

  float v = 0.0f;
  if (b < B) {
    #pragma unroll
    for (int m = 0; m < NBLOCKS / 64; ++m)
      v += ws[b * NBLOCKS + lane + (m << 6)];
  }
  #pragma unroll
  for (int off = 32; off > 0; off >>= 1) v += __shfl_xor(v, off);

  __shared__ float sh[BDIM];
  if (lane == 0 && b < B) {
    const int len = lens[b];
    sh[b] = (len > 0) ? (1.0f - v / (float)len) : 0.0f;
  }
  __syncthreads();
  if (threadIdx.x == 0) {
    float t = 0.0f;
    for (int i = 0; i < B; ++i) t += sh[i];
    out[0] = t / (float)B;
  }
}

extern "C" void kernel_launch(void* const* d_in, const int* in_sizes, int n_in,
                              void* d_out, int out_size, void* d_ws, size_t ws_size,
                              hipStream_t stream) {
  const float* stat = (const float*)d_in[0];
  const float* con  = (const float*)d_in[1];
  const int*   lens = (const int*)d_in[2];
  float*       out  = (float*)d_out;
  float*       ws   = (float*)d_ws;

  const int B = in_sizes[2];           // 16

  dim3 grid1(NBLOCKS);
  dim3 blk1(256);
  hipLaunchKernelGGL(cos_partial_kernel, grid1, blk1, 0, stream, stat, con, lens, ws);

  dim3 grid2(1);
  dim3 blk2(64 * BDIM);                // 1024 threads: one wave per instance
  hipLaunchKernelGGL(cos_final_kernel, grid2, blk2, 0, stream, ws, lens, out, B);
}

// Round 4
// 20.489 us; speedup vs baseline: 1.1943x; 1.0536x over previous
//
#include <hip/hip_runtime.h>

#define NROWS 4096
#define DDIM 256
#define BDIM 16
#define RBLKS 256           // row-blocks; each covers 16 rows
#define NB1 (RBLKS * 4)     // 1024 blocks; blockIdx>>8 selects the 4-instance set

// Kernel 1: block (bset, rblk) handles instances b in [4*bset, 4*bset+4) for
// rows [16*rblk, 16*rblk+16). Within a wave: 4 groups of 16 lanes, group g owns
// one row; lane j covers cols {4j+64m : m=0..3} (one float4 each; each 16-lane
// group load is 256 B contiguous -> fully coalesced).
// Reduction: 4-stage butterfly within 16 lanes -> only 3 cross-lane ops/row.
__global__ __launch_bounds__(256, 4) void cos_partial_kernel(
    const float* __restrict__ stat, const float* __restrict__ con,
    const int* __restrict__ lens, float* __restrict__ ws) {
  const int rblk = blockIdx.x & (RBLKS - 1);
  const int bset = blockIdx.x >> 8;          // 0..3
  const int wave = threadIdx.x >> 6;
  const int lane = threadIdx.x & 63;
  const int g    = lane >> 4;                // row-group within wave
  const int j    = lane & 15;                // col-lane within group

  const int n  = rblk * 16 + wave * 4 + g;   // this lane's row
  const int b0 = bset * 4;

  float acc[4];

  #pragma unroll
  for (int bi = 0; bi < 4; ++bi) {
    const int b    = b0 + bi;
    const int len  = lens[b];
    const bool valid = (n < len);

    float dot = 0.0f, ns = 0.0f, nc = 0.0f;
    if (valid) {  // invalid rows: zero memory traffic
      const size_t base = (size_t)b * (NROWS * DDIM) + (size_t)n * DDIM + (j << 2);
      const float* pa = stat + base;
      const float* pc = con + base;
      #pragma unroll
      for (int m = 0; m < 4; ++m) {
        const float4 a = *reinterpret_cast<const float4*>(pa + (m << 6));
        const float4 c = *reinterpret_cast<const float4*>(pc + (m << 6));
        dot = fmaf(a.x, c.x, fmaf(a.y, c.y, fmaf(a.z, c.z, fmaf(a.w, c.w, dot))));
        ns  = fmaf(a.x, a.x, fmaf(a.y, a.y, fmaf(a.z, a.z, fmaf(a.w, a.w, ns))));
        nc  = fmaf(c.x, c.x, fmaf(c.y, c.y, fmaf(c.z, c.z, fmaf(c.w, c.w, nc))));
      }
    }
    // 4-stage butterfly within each 16-lane group (all lanes participate)
    #pragma unroll
    for (int off = 1; off < 16; off <<= 1) {
      dot += __shfl_xor(dot, off);
      ns  += __shfl_xor(ns,  off);
      nc  += __shfl_xor(nc,  off);
    }
    // eps clamp unreachable for chi2(256) norms; select kills NaN on empty rows
    const float cosv = dot * rsqrtf(ns) * rsqrtf(nc);
    acc[bi] = valid ? cosv : 0.0f;
  }

  // Each of the 16 lanes in a group holds its row's cos -> wave sum = 16x true.
  __shared__ float sh[4][4];
  #pragma unroll
  for (int bi = 0; bi < 4; ++bi) {
    float v = acc[bi];
    #pragma unroll
    for (int off = 1; off < 64; off <<= 1) v += __shfl_xor(v, off);
    if (lane == 0) sh[wave][bi] = v * (1.0f / 16.0f);
  }
  __syncthreads();
  if (threadIdx.x < 4) {
    const int b = b0 + threadIdx.x;
    ws[b * RBLKS + rblk] =
        sh[0][threadIdx.x] + sh[1][threadIdx.x] + sh[2][threadIdx.x] + sh[3][threadIdx.x];
  }
}

// Kernel 2: single block, 1024 threads. Wave b reduces the 256 partials of
// instance b (coalesced), thread 0 combines the B losses sequentially.
__global__ __launch_bounds__(1024) void cos_final_kernel(
    const float* __restrict__ ws, const int* __restrict__ lens,
    float* __restrict__ out, int B) {
  const int b    = threadIdx.x >> 6;
  const int lane = threadIdx.x & 63;

  float v = 0.0f;
  if (b < B) {
    #pragma unroll
    for (int m = 0; m < RBLKS / 64; ++m)
      v += ws[b * RBLKS + (m << 6) + lane];
  }
  #pragma unroll
  for (int off = 1; off < 64; off <<= 1) v += __shfl_xor(v, off);

  __shared__ float sh[BDIM];
  if (lane == 0 && b < B) {
    const int len = lens[b];
    sh[b] = (len > 0) ? (1.0f - v / (float)len) : 0.0f;
  }
  __syncthreads();
  if (threadIdx.x == 0) {
    float t = 0.0f;
    for (int i = 0; i < B; ++i) t += sh[i];
    out[0] = t / (float)B;
  }
}

extern "C" void kernel_launch(void* const* d_in, const int* in_sizes, int n_in,
                              void* d_out, int out_size, void* d_ws, size_t ws_size,
                              hipStream_t stream) {
  const float* stat = (const float*)d_in[0];
  const float* con  = (const float*)d_in[1];
  const int*   lens = (const int*)d_in[2];
  float*       out  = (float*)d_out;
  float*       ws   = (float*)d_ws;

  const int B = in_sizes[2];           // 16

  dim3 grid1(NB1);
  dim3 blk1(256);
  hipLaunchKernelGGL(cos_partial_kernel, grid1, blk1, 0, stream, stat, con, lens, ws);

  dim3 grid2(1);
  dim3 blk2(64 * BDIM);                // 1024 threads: one wave per instance
  hipLaunchKernelGGL(cos_final_kernel, grid2, blk2, 0, stream, ws, lens, out, B);
}